// Round 15
// baseline (113.944 us; speedup 1.0000x reference)
//
#include <hip/hip_runtime.h>
#include <math.h>

#define NB 512
#define MODES 1000
#define PI_D 3.14159265358979323846

// ws layout (bytes)
#define OFF_PART   0          // double2[192] per-(k,m) weight row sums
#define OFF_SCAL   4096       // double[4]: c0re,c0im,c1re,c1im
#define OFF_T2RE   4224       // double[64]
#define OFF_T2IM   4736       // double[64]
#define OFF_GP     5248       // float[64]  g(+1)
#define OFF_CNT    5504       // int irregular count
#define OFF_W2T    16384      // float[64000]  W2 transposed [o][j]
#define OFF_S2     2621440    // float[512000] s2 value [b*1000+f]
#define OFF_IRR    4718592    // int[512000] irregular indices
#define OFF_SG     13107200   // float[512*1000] sgn [b][f] row-major
#define OFF_EHI    19398656   // ushort[1024*1024] bf16 hi of E[o][f]
#define OFF_ELO    21495808   // ushort[1024*1024] bf16 lo of E[o][f]
#define OFF_SGNB   23592960   // ushort[512*1024] bf16 sgn [b][f], f>=1000 zero
#define OFF_H      24641536   // float[512*1024] h pre-bias

typedef short short8 __attribute__((ext_vector_type(8)));
typedef float f32x4 __attribute__((ext_vector_type(4)));

__device__ __forceinline__ double retanh_d(double a, double b) {
    if (fabs(a) > 20.0) return a > 0.0 ? 1.0 : -1.0;
    double e2 = exp(2.0 * a);
    double em2 = 1.0 / e2;
    return (e2 - em2) / (e2 + em2 + 2.0 * cos(2.0 * b));
}

__device__ __forceinline__ unsigned short f2bf(float x) {
    unsigned u = __float_as_uint(x);
    unsigned r = (u + 0x7FFFu + ((u >> 16) & 1u)) >> 16;
    return (unsigned short)r;
}

// Preamble: bid<192 row sums; 192..441 W2 transpose; 442..489 EHI row-pad;
// 490..537 ELO row-pad; 538..561 sgnb f-pad. Also resets cnt.
__global__ void k_misc(const float* __restrict__ w0r, const float* __restrict__ w0i,
                       const float* __restrict__ w1r, const float* __restrict__ w1i,
                       const float* __restrict__ w2r, const float* __restrict__ w2i,
                       const float* __restrict__ w2, char* ws) {
    int bid = blockIdx.x, t = threadIdx.x;
    if (bid == 0 && t == 0) *(int*)(ws + OFF_CNT) = 0;
    if (bid < 192) {
        int k = bid >> 6, m = bid & 63;
        const float* wr = (k == 0) ? w0r : (k == 1) ? w1r : w2r;
        const float* wi = (k == 0) ? w0i : (k == 1) ? w1i : w2i;
        double sr = 0.0, si = 0.0;
        for (int c = t; c < MODES; c += 256) {
            sr += (double)wr[m * MODES + c];
            si += (double)wi[m * MODES + c];
        }
        __shared__ double lr[256], li[256];
        lr[t] = sr; li[t] = si; __syncthreads();
        for (int s = 128; s > 0; s >>= 1) {
            if (t < s) { lr[t] += lr[t + s]; li[t] += li[t + s]; }
            __syncthreads();
        }
        if (t == 0) {
            double2* p = (double2*)(ws + OFF_PART);
            p[k * 64 + m] = make_double2(lr[0], li[0]);
        }
    } else if (bid < 442) {
        int idx = (bid - 192) * 256 + t;   // < 64000
        int o = idx >> 6, j = idx & 63;
        ((float*)(ws + OFF_W2T))[idx] = w2[j * MODES + o];
    } else if (bid < 490) {
        int idx = (bid - 442) * 256 + t;   // rows 1000..1023 of EHI
        ((unsigned*)(ws + OFF_EHI))[512000 + idx] = 0u;
    } else if (bid < 538) {
        int idx = (bid - 490) * 256 + t;
        ((unsigned*)(ws + OFF_ELO))[512000 + idx] = 0u;
    } else {
        int idx = (bid - 538) * 256 + t;   // < 6144
        if (idx < 6144) {
            int b = idx / 12, u = idx % 12;
            ((unsigned*)(ws + OFF_SGNB))[b * 512 + 500 + u] = 0u;
        }
    }
}

// Main pass: per-block prep (recomputed from part[], ~12k f64 FLOP) then
// bid<1000: s-gather unit; bid>=1000: E-stream unit (identical to R13 bodies).
__global__ void __launch_bounds__(512) k_sEb(const float* __restrict__ w1,
                                             const float* __restrict__ params,
                                             char* ws) {
    __shared__ double a0r[64], a0i[64], a1r[64], a1i[64];
    __shared__ double sre[64], sim[64], tc[64], tsn[64];
    __shared__ double ppr[8][64], ppi[8][64];
    __shared__ double scal_sh[4];
    __shared__ double t2r_sh[64], t2i_sh[64];
    __shared__ __align__(16) float gp_sh[64];
    int bid = blockIdx.x, t = threadIdx.x;
    const double2* part = (const double2*)(ws + OFF_PART);
    if (t < 64) {
        double2 v0 = part[t], v1 = part[64 + t], v2 = part[128 + t];
        a0r[t] = v0.x; a0i[t] = v0.y;
        a1r[t] = v1.x; a1i[t] = v1.y;
        sre[t] = v2.x; sim[t] = v2.y;
    } else if (t < 128) {
        int r = t - 64;
        double s, c;
        sincos((double)r * (PI_D / 32.0), &s, &c);
        tc[r] = c; tsn[r] = s;
    }
    __syncthreads();
    for (int s = 32; s > 0; s >>= 1) {
        if (t < s) {
            a0r[t] += a0r[t + s]; a0i[t] += a0i[t + s];
            a1r[t] += a1r[t + s]; a1i[t] += a1i[t + s];
        }
        __syncthreads();
    }
    if (t == 0) {
        scal_sh[0] = a0r[0]; scal_sh[1] = a0i[0];
        scal_sh[2] = a1r[0]; scal_sh[3] = a1i[0];
    }
    {   // DFT: j = t&63, q = t>>6 in 0..7, 8 terms each
        int j = t & 63, q = t >> 6;
        double tr = 0.0, ti = 0.0;
        for (int mm = q * 8; mm < q * 8 + 8; ++mm) {
            int r = (j * mm) & 63;
            double c = tc[r], s = tsn[r];
            tr += sre[mm] * c - sim[mm] * s;
            ti += sre[mm] * s + sim[mm] * c;
        }
        ppr[q][j] = tr; ppi[q][j] = ti;
    }
    __syncthreads();
    if (t < 64) {
        double tr = 0.0, ti = 0.0;
#pragma unroll
        for (int q = 0; q < 8; ++q) { tr += ppr[q][t]; ti += ppi[q][t]; }
        t2r_sh[t] = tr; t2i_sh[t] = ti;
        gp_sh[t] = (float)retanh_d(tr, ti);
    }
    __syncthreads();
    if (bid == 0) {   // persist for k_final's correction path
        if (t < 4) ((double*)(ws + OFF_SCAL))[t] = scal_sh[t];
        if (t < 64) {
            ((double*)(ws + OFF_T2RE))[t] = t2r_sh[t];
            ((double*)(ws + OFF_T2IM))[t] = t2i_sh[t];
            ((float*)(ws + OFF_GP))[t] = gp_sh[t];
        }
    }

    if (bid < 1000) {
        int idx = bid * 512 + t;   // < 512000
        double c0r = scal_sh[0], c0i = scal_sh[1], c1r = scal_sh[2], c1i = scal_sh[3];
        float p0 = params[(size_t)idx * 64];
        double s1 = retanh_d((double)p0 * c0r, (double)p0 * c0i);
        float s1f = (float)s1;
        double s2 = retanh_d((double)s1f * c1r, (double)s1f * c1i);
        float s2f = (float)s2;
        float sg; bool irr = false;
        if (s2f == 1.0f)       sg = 1.0f;
        else if (s2f == -1.0f) sg = -1.0f;
        else { sg = (s2f >= 0.0f) ? 1.0f : -1.0f; irr = true; }
        ((float*)(ws + OFF_SG))[idx] = sg;
        ((float*)(ws + OFF_S2))[idx] = s2f;
        int b = idx / 1000, f = idx - b * 1000;
        ((unsigned short*)(ws + OFF_SGNB))[(size_t)b * 1024 + f] =
            (sg > 0.0f) ? (unsigned short)0x3F80 : (unsigned short)0xBF80;
        if (irr) {
            int pos = atomicAdd((int*)(ws + OFF_CNT), 1);
            ((int*)(ws + OFF_IRR))[pos] = idx;
        }
    } else {
        int eu = bid - 1000;         // [0, 4000)
        int o = eu >> 2, chunk = eu & 3;
        const float4* w4 = (const float4*)w1;
        const float4* gp4 = (const float4*)gp_sh;
        float4 g = gp4[t & 15];
        unsigned short* ehi = (unsigned short*)(ws + OFF_EHI);
        unsigned short* elo = (unsigned short*)(ws + OFF_ELO);
        size_t rowbase = (size_t)o * 16000;
        int cbase = chunk * 4096 + t;
        float4 v[8];
#pragma unroll
        for (int k = 0; k < 8; ++k) {
            int gidx = cbase + k * 512;
            int cidx = (gidx < 15999) ? gidx : 15999;   // clamp: always in-bounds
            v[k] = w4[rowbase + cidx];
        }
#pragma unroll
        for (int k = 0; k < 8; ++k) {
            int gidx = cbase + k * 512;
            float a = v[k].x * g.x + v[k].y * g.y + v[k].z * g.z + v[k].w * g.w;
            a = (gidx < 16000) ? a : 0.0f;
            a += __shfl_xor(a, 1);
            a += __shfl_xor(a, 2);
            a += __shfl_xor(a, 4);
            a += __shfl_xor(a, 8);
            if ((t & 15) == 0) {
                int f = chunk * 256 + k * 32 + (t >> 4);  // <= 1023
                unsigned short hi = f2bf(a);
                float hif = __uint_as_float((unsigned)hi << 16);
                unsigned short lo = f2bf(a - hif);
                ehi[(size_t)o * 1024 + f] = hi;
                elo[(size_t)o * 1024 + f] = lo;
            }
        }
    }
}

// h[b][o] = sum_f sgn[b,f]*E[o,f] via MFMA, bf16 two-term split, no LDS.
__global__ void __launch_bounds__(128) k_gemm(char* ws) {
    const unsigned short* sgnb = (const unsigned short*)(ws + OFF_SGNB);
    const unsigned short* ehi  = (const unsigned short*)(ws + OFF_EHI);
    const unsigned short* elo  = (const unsigned short*)(ws + OFF_ELO);
    float* h = (float*)(ws + OFF_H);
    int strip = blockIdx.x;      // 0..15  (64 o-cols)
    int btile = blockIdx.y;      // 0..31  (16 b-rows)
    int t = threadIdx.x;         // 128 = 2 waves
    int wave = t >> 6, l = t & 63;
    int rc = l & 15, grp = l >> 4;
    int b0 = btile * 16;
    int o0 = strip * 64 + wave * 32;
    f32x4 acc0 = {0.f, 0.f, 0.f, 0.f}, acc1 = {0.f, 0.f, 0.f, 0.f};
    const unsigned short* ap  = sgnb + (size_t)(b0 + rc) * 1024 + grp * 8;
    const unsigned short* bh0 = ehi + (size_t)(o0 + rc) * 1024 + grp * 8;
    const unsigned short* bl0 = elo + (size_t)(o0 + rc) * 1024 + grp * 8;
#pragma unroll 4
    for (int s = 0; s < 32; ++s) {
        short8 af  = *(const short8*)(ap + s * 32);
        short8 h0  = *(const short8*)(bh0 + s * 32);
        short8 l0  = *(const short8*)(bl0 + s * 32);
        short8 h1  = *(const short8*)(bh0 + 16 * 1024 + s * 32);
        short8 l1  = *(const short8*)(bl0 + 16 * 1024 + s * 32);
        acc0 = __builtin_amdgcn_mfma_f32_16x16x32_bf16(af, h0, acc0, 0, 0, 0);
        acc0 = __builtin_amdgcn_mfma_f32_16x16x32_bf16(af, l0, acc0, 0, 0, 0);
        acc1 = __builtin_amdgcn_mfma_f32_16x16x32_bf16(af, h1, acc1, 0, 0, 0);
        acc1 = __builtin_amdgcn_mfma_f32_16x16x32_bf16(af, l1, acc1, 0, 0, 0);
    }
#pragma unroll
    for (int r = 0; r < 4; ++r) {
        h[(size_t)(b0 + grp * 4 + r) * 1024 + o0 + rc]      = acc0[r];
        h[(size_t)(b0 + grp * 4 + r) * 1024 + o0 + 16 + rc] = acc1[r];
    }
}

// Fused epilogue: h + b1; rare exact corrections; tanh; dot W2t; sigmoid.
__global__ void k_final(const float* __restrict__ w1, const float* __restrict__ b1,
                        const float* __restrict__ b2, float* __restrict__ out, char* ws) {
    int b = blockIdx.x, t = threadIdx.x;   // 512 blocks x 256
    const float* hbuf = (const float*)(ws + OFF_H);
    __shared__ float h[MODES];
    __shared__ float part[4][64];
    __shared__ __align__(16) float cv[64];
    for (int o = t; o < MODES; o += 256)
        h[o] = hbuf[(size_t)b * 1024 + o] + b1[o];
    __syncthreads();
    int cnt = *(const int*)(ws + OFF_CNT);
    if (cnt > 0) {
        const int* irr     = (const int*)(ws + OFF_IRR);
        const float* s2a   = (const float*)(ws + OFF_S2);
        const float* sgn   = (const float*)(ws + OFF_SG);
        const double* t2re = (const double*)(ws + OFF_T2RE);
        const double* t2im = (const double*)(ws + OFF_T2IM);
        const float* gp    = (const float*)(ws + OFF_GP);
        for (int e = 0; e < cnt; ++e) {
            int idx = irr[e];
            int bb = idx / 1000;
            if (bb != b) continue;              // uniform per block
            int f = idx - bb * 1000;
            float s2 = s2a[idx];
            float sg = sgn[idx];
            if (t < 64) {
                double g = retanh_d((double)s2 * t2re[t], (double)s2 * t2im[t]);
                cv[t] = (float)g - sg * gp[t];
            }
            __syncthreads();
            const float4* w4 = (const float4*)w1;
            const float4* c4 = (const float4*)cv;
            for (int o = t; o < MODES; o += 256) {
                size_t base = (size_t)o * 16000 + (size_t)f * 16;
                float a = 0.0f;
#pragma unroll
                for (int r = 0; r < 16; ++r) {
                    float4 w = w4[base + r];
                    float4 c = c4[r];
                    a += w.x * c.x + w.y * c.y + w.z * c.z + w.w * c.w;
                }
                h[o] += a;
            }
            __syncthreads();
        }
    }
    for (int o = t; o < MODES; o += 256) h[o] = tanhf(h[o]);
    __syncthreads();
    const float* w2t = (const float*)(ws + OFF_W2T);
    int j = t & 63, c = t >> 6;
    float acc = 0.0f;
    for (int o = c * 250; o < c * 250 + 250; ++o) acc += h[o] * w2t[o * 64 + j];
    part[c][j] = acc;
    __syncthreads();
    if (t < 64) {
        float s = part[0][t] + part[1][t] + part[2][t] + part[3][t] + b2[t];
        out[b * 64 + t] = 1.0f / (1.0f + expf(-s));
    }
}

extern "C" void kernel_launch(void* const* d_in, const int* in_sizes, int n_in,
                              void* d_out, int out_size, void* d_ws, size_t ws_size,
                              hipStream_t stream) {
    const float* params = (const float*)d_in[0];
    const float* w0r = (const float*)d_in[1];
    const float* w0i = (const float*)d_in[2];
    const float* w1r = (const float*)d_in[3];
    const float* w1i = (const float*)d_in[4];
    const float* w2r = (const float*)d_in[5];
    const float* w2i = (const float*)d_in[6];
    const float* lin1w = (const float*)d_in[7];
    const float* lin1b = (const float*)d_in[8];
    const float* lin2w = (const float*)d_in[9];
    const float* lin2b = (const float*)d_in[10];
    char* ws = (char*)d_ws;
    float* out = (float*)d_out;

    k_misc<<<562, 256, 0, stream>>>(w0r, w0i, w1r, w1i, w2r, w2i, lin2w, ws);
    k_sEb<<<5000, 512, 0, stream>>>(lin1w, params, ws);
    k_gemm<<<dim3(16, 32), 128, 0, stream>>>(ws);
    k_final<<<512, 256, 0, stream>>>(lin1w, lin1b, lin2b, out, ws);
}

// Round 16
// 107.614 us; speedup vs baseline: 1.0588x; 1.0588x over previous
//
#include <hip/hip_runtime.h>
#include <math.h>

#define NB 512
#define MODES 1000
#define PI_D 3.14159265358979323846

// ws layout (bytes)
#define OFF_PART   0          // double2[192] per-(k,m) weight row sums
#define OFF_SCAL   4096       // double[4]: c0re,c0im,c1re,c1im
#define OFF_T2RE   4224       // double[64]
#define OFF_T2IM   4736       // double[64]
#define OFF_GP     5248       // float[64]  g(+1)
#define OFF_CNT    5504       // int irregular count
#define OFF_W2T    16384      // float[64000]  W2 transposed [o][j]
#define OFF_S2     2621440    // float[512000] s2 value [b*1000+f]
#define OFF_IRR    4718592    // int[512000] irregular indices
#define OFF_SG     13107200   // float[512*1000] sgn [b][f] row-major
#define OFF_EHI    19398656   // ushort[1024*1024] bf16 hi of E[o][f]
#define OFF_ELO    21495808   // ushort[1024*1024] bf16 lo of E[o][f]
#define OFF_SGNB   23592960   // ushort[512*1024] bf16 sgn [b][f], f>=1000 zero
#define OFF_H      24641536   // float[4][512][1024] split-K partials (8 MB)
#define HP_STRIDE  524288     // 512*1024 floats

typedef short short8 __attribute__((ext_vector_type(8)));
typedef float f32x4 __attribute__((ext_vector_type(4)));

__device__ __forceinline__ double retanh_d(double a, double b) {
    if (fabs(a) > 20.0) return a > 0.0 ? 1.0 : -1.0;
    double e2 = exp(2.0 * a);
    double em2 = 1.0 / e2;
    return (e2 - em2) / (e2 + em2 + 2.0 * cos(2.0 * b));
}

__device__ __forceinline__ unsigned short f2bf(float x) {
    unsigned u = __float_as_uint(x);
    unsigned r = (u + 0x7FFFu + ((u >> 16) & 1u)) >> 16;
    return (unsigned short)r;
}

// Preamble: bid<192 row sums; 192..441 W2 transpose; 442..489 EHI row-pad;
// 490..537 ELO row-pad; 538..561 sgnb f-pad.
__global__ void k_misc(const float* __restrict__ w0r, const float* __restrict__ w0i,
                       const float* __restrict__ w1r, const float* __restrict__ w1i,
                       const float* __restrict__ w2r, const float* __restrict__ w2i,
                       const float* __restrict__ w2, char* ws) {
    int bid = blockIdx.x, t = threadIdx.x;
    if (bid < 192) {
        int k = bid >> 6, m = bid & 63;
        const float* wr = (k == 0) ? w0r : (k == 1) ? w1r : w2r;
        const float* wi = (k == 0) ? w0i : (k == 1) ? w1i : w2i;
        double sr = 0.0, si = 0.0;
        for (int c = t; c < MODES; c += 256) {
            sr += (double)wr[m * MODES + c];
            si += (double)wi[m * MODES + c];
        }
        __shared__ double lr[256], li[256];
        lr[t] = sr; li[t] = si; __syncthreads();
        for (int s = 128; s > 0; s >>= 1) {
            if (t < s) { lr[t] += lr[t + s]; li[t] += li[t + s]; }
            __syncthreads();
        }
        if (t == 0) {
            double2* p = (double2*)(ws + OFF_PART);
            p[k * 64 + m] = make_double2(lr[0], li[0]);
        }
    } else if (bid < 442) {
        int idx = (bid - 192) * 256 + t;   // < 64000
        int o = idx >> 6, j = idx & 63;
        ((float*)(ws + OFF_W2T))[idx] = w2[j * MODES + o];
    } else if (bid < 490) {
        int idx = (bid - 442) * 256 + t;   // rows 1000..1023 of EHI
        ((unsigned*)(ws + OFF_EHI))[512000 + idx] = 0u;
    } else if (bid < 538) {
        int idx = (bid - 490) * 256 + t;
        ((unsigned*)(ws + OFF_ELO))[512000 + idx] = 0u;
    } else {
        int idx = (bid - 538) * 256 + t;   // < 6144
        if (idx < 6144) {
            int b = idx / 12, u = idx % 12;
            ((unsigned*)(ws + OFF_SGNB))[b * 512 + 500 + u] = 0u;
        }
    }
}

// c0,c1 totals; T2 via 64-pt inverse DFT with LDS twiddle table; gp = g(+1); cnt = 0.
__global__ void k_prep(char* ws) {
    int t = threadIdx.x;           // 256
    int j = t & 63, q = t >> 6;    // q in 0..3
    double2* part = (double2*)(ws + OFF_PART);
    double* scal  = (double*)(ws + OFF_SCAL);
    double* t2re  = (double*)(ws + OFF_T2RE);
    double* t2im  = (double*)(ws + OFF_T2IM);
    float*  gp    = (float*)(ws + OFF_GP);
    __shared__ double a1[128], a2[128];
    __shared__ double sre[64], sim[64];
    __shared__ double tc[64], tsn[64];
    __shared__ double pr[4][64], pi_[4][64];
    if (t < 128) {
        double2 v = part[t];       // k = t>>6, m = t&63
        a1[t] = v.x; a2[t] = v.y;
    }
    if (t < 64) {
        double2 v = part[128 + t];
        sre[t] = v.x; sim[t] = v.y;
    }
    if (t >= 128 && t < 192) {     // twiddle table: one sincos per lane
        int r = t - 128;
        double s, c;
        sincos((double)r * (PI_D / 32.0), &s, &c);
        tc[r] = c; tsn[r] = s;
    }
    __syncthreads();
    for (int s = 32; s > 0; s >>= 1) {
        if (t < 128 && (t & 63) < s) { a1[t] += a1[t + s]; a2[t] += a2[t + s]; }
        __syncthreads();
    }
    if (t < 2) { scal[2 * t] = a1[t * 64]; scal[2 * t + 1] = a2[t * 64]; }
    double tr = 0.0, ti = 0.0;
    for (int mm = q * 16; mm < q * 16 + 16; ++mm) {
        int r = (j * mm) & 63;
        double c = tc[r], s = tsn[r];
        tr += sre[mm] * c - sim[mm] * s;
        ti += sre[mm] * s + sim[mm] * c;
    }
    pr[q][j] = tr; pi_[q][j] = ti;
    __syncthreads();
    if (t < 64) {
        double trr = pr[0][t] + pr[1][t] + pr[2][t] + pr[3][t];
        double tii = pi_[0][t] + pi_[1][t] + pi_[2][t] + pi_[3][t];
        t2re[t] = trr; t2im[t] = tii;
        gp[t] = (float)retanh_d(trr, tii);
    }
    if (t == 0) *(int*)(ws + OFF_CNT) = 0;
}

// s2/sgn gather + classify (f64 chain isolated here). 1000 blocks x 512.
__global__ void k_s(const float* __restrict__ params, char* ws) {
    int idx = blockIdx.x * 512 + threadIdx.x;   // < 512000
    const double* scal = (const double*)(ws + OFF_SCAL);
    double c0r = scal[0], c0i = scal[1], c1r = scal[2], c1i = scal[3];
    float p0 = params[(size_t)idx * 64];
    double s1 = retanh_d((double)p0 * c0r, (double)p0 * c0i);
    float s1f = (float)s1;
    double s2 = retanh_d((double)s1f * c1r, (double)s1f * c1i);
    float s2f = (float)s2;
    float sg; bool irr = false;
    if (s2f == 1.0f)       sg = 1.0f;
    else if (s2f == -1.0f) sg = -1.0f;
    else { sg = (s2f >= 0.0f) ? 1.0f : -1.0f; irr = true; }
    ((float*)(ws + OFF_SG))[idx] = sg;
    ((float*)(ws + OFF_S2))[idx] = s2f;
    int b = idx / 1000, f = idx - b * 1000;
    ((unsigned short*)(ws + OFF_SGNB))[(size_t)b * 1024 + f] =
        (sg > 0.0f) ? (unsigned short)0x3F80 : (unsigned short)0xBF80;
    if (irr) {
        int pos = atomicAdd((int*)(ws + OFF_CNT), 1);
        ((int*)(ws + OFF_IRR))[pos] = idx;
    }
}

// Pure fp32 E-stream: 4000 blocks x 512, 8 branchless clamped loads hoisted.
__global__ void __launch_bounds__(512) k_E(const float* __restrict__ w1, char* ws) {
    int bid = blockIdx.x;
    int o = bid >> 2, chunk = bid & 3;
    int t = threadIdx.x;
    const float4* w4 = (const float4*)w1;
    const float4* gp4 = (const float4*)(ws + OFF_GP);
    float4 g = gp4[t & 15];
    unsigned short* ehi = (unsigned short*)(ws + OFF_EHI);
    unsigned short* elo = (unsigned short*)(ws + OFF_ELO);
    size_t rowbase = (size_t)o * 16000;
    int cbase = chunk * 4096 + t;
    float4 v[8];
#pragma unroll
    for (int k = 0; k < 8; ++k) {
        int gidx = cbase + k * 512;
        int cidx = (gidx < 15999) ? gidx : 15999;
        v[k] = w4[rowbase + cidx];
    }
#pragma unroll
    for (int k = 0; k < 8; ++k) {
        int gidx = cbase + k * 512;
        float a = v[k].x * g.x + v[k].y * g.y + v[k].z * g.z + v[k].w * g.w;
        a = (gidx < 16000) ? a : 0.0f;
        a += __shfl_xor(a, 1);
        a += __shfl_xor(a, 2);
        a += __shfl_xor(a, 4);
        a += __shfl_xor(a, 8);
        if ((t & 15) == 0) {
            int f = chunk * 256 + k * 32 + (t >> 4);  // <= 1023
            unsigned short hi = f2bf(a);
            float hif = __uint_as_float((unsigned)hi << 16);
            unsigned short lo = f2bf(a - hif);
            ehi[(size_t)o * 1024 + f] = hi;
            elo[(size_t)o * 1024 + f] = lo;
        }
    }
}

// hp[z][b][o] += sum over K-chunk z: split-K x4 MFMA, 4096 waves (4/SIMD).
__global__ void __launch_bounds__(128) k_gemm(char* ws) {
    const unsigned short* sgnb = (const unsigned short*)(ws + OFF_SGNB);
    const unsigned short* ehi  = (const unsigned short*)(ws + OFF_EHI);
    const unsigned short* elo  = (const unsigned short*)(ws + OFF_ELO);
    int strip = blockIdx.x;      // 0..15  (64 o-cols)
    int btile = blockIdx.y;      // 0..31  (16 b-rows)
    int z     = blockIdx.z;      // 0..3   (K-chunk of 256)
    float* hp = (float*)(ws + OFF_H) + (size_t)z * HP_STRIDE;
    int t = threadIdx.x;         // 128 = 2 waves
    int wave = t >> 6, l = t & 63;
    int rc = l & 15, grp = l >> 4;
    int b0 = btile * 16;
    int o0 = strip * 64 + wave * 32;
    f32x4 acc0 = {0.f, 0.f, 0.f, 0.f}, acc1 = {0.f, 0.f, 0.f, 0.f};
    const unsigned short* ap  = sgnb + (size_t)(b0 + rc) * 1024 + z * 256 + grp * 8;
    const unsigned short* bh0 = ehi + (size_t)(o0 + rc) * 1024 + z * 256 + grp * 8;
    const unsigned short* bl0 = elo + (size_t)(o0 + rc) * 1024 + z * 256 + grp * 8;
#pragma unroll
    for (int s = 0; s < 8; ++s) {
        short8 af  = *(const short8*)(ap + s * 32);
        short8 h0  = *(const short8*)(bh0 + s * 32);
        short8 l0  = *(const short8*)(bl0 + s * 32);
        short8 h1  = *(const short8*)(bh0 + 16 * 1024 + s * 32);
        short8 l1  = *(const short8*)(bl0 + 16 * 1024 + s * 32);
        acc0 = __builtin_amdgcn_mfma_f32_16x16x32_bf16(af, h0, acc0, 0, 0, 0);
        acc0 = __builtin_amdgcn_mfma_f32_16x16x32_bf16(af, l0, acc0, 0, 0, 0);
        acc1 = __builtin_amdgcn_mfma_f32_16x16x32_bf16(af, h1, acc1, 0, 0, 0);
        acc1 = __builtin_amdgcn_mfma_f32_16x16x32_bf16(af, l1, acc1, 0, 0, 0);
    }
    // C/D: col = lane&15, row = (lane>>4)*4 + reg   [m89-verified]
#pragma unroll
    for (int r = 0; r < 4; ++r) {
        hp[(size_t)(b0 + grp * 4 + r) * 1024 + o0 + rc]      = acc0[r];
        hp[(size_t)(b0 + grp * 4 + r) * 1024 + o0 + 16 + rc] = acc1[r];
    }
}

// Fused epilogue: h = sum_z hp + b1; rare exact corrections; tanh; dot W2t; sigmoid.
__global__ void k_final(const float* __restrict__ w1, const float* __restrict__ b1,
                        const float* __restrict__ b2, float* __restrict__ out, char* ws) {
    int b = blockIdx.x, t = threadIdx.x;   // 512 blocks x 256
    const float* hp = (const float*)(ws + OFF_H);
    __shared__ float h[MODES];
    __shared__ float part[4][64];
    __shared__ __align__(16) float cv[64];
    for (int o = t; o < MODES; o += 256) {
        size_t base = (size_t)b * 1024 + o;
        h[o] = hp[base] + hp[base + HP_STRIDE] + hp[base + 2 * HP_STRIDE]
             + hp[base + 3 * HP_STRIDE] + b1[o];
    }
    __syncthreads();
    int cnt = *(const int*)(ws + OFF_CNT);
    if (cnt > 0) {
        const int* irr     = (const int*)(ws + OFF_IRR);
        const float* s2a   = (const float*)(ws + OFF_S2);
        const float* sgn   = (const float*)(ws + OFF_SG);
        const double* t2re = (const double*)(ws + OFF_T2RE);
        const double* t2im = (const double*)(ws + OFF_T2IM);
        const float* gp    = (const float*)(ws + OFF_GP);
        for (int e = 0; e < cnt; ++e) {
            int idx = irr[e];
            int bb = idx / 1000;
            if (bb != b) continue;              // uniform per block
            int f = idx - bb * 1000;
            float s2 = s2a[idx];
            float sg = sgn[idx];
            if (t < 64) {
                double g = retanh_d((double)s2 * t2re[t], (double)s2 * t2im[t]);
                cv[t] = (float)g - sg * gp[t];
            }
            __syncthreads();
            const float4* w4 = (const float4*)w1;
            const float4* c4 = (const float4*)cv;
            for (int o = t; o < MODES; o += 256) {
                size_t base = (size_t)o * 16000 + (size_t)f * 16;
                float a = 0.0f;
#pragma unroll
                for (int r = 0; r < 16; ++r) {
                    float4 w = w4[base + r];
                    float4 c = c4[r];
                    a += w.x * c.x + w.y * c.y + w.z * c.z + w.w * c.w;
                }
                h[o] += a;
            }
            __syncthreads();
        }
    }
    for (int o = t; o < MODES; o += 256) h[o] = tanhf(h[o]);
    __syncthreads();
    const float* w2t = (const float*)(ws + OFF_W2T);
    int j = t & 63, c = t >> 6;
    float acc = 0.0f;
    for (int o = c * 250; o < c * 250 + 250; ++o) acc += h[o] * w2t[o * 64 + j];
    part[c][j] = acc;
    __syncthreads();
    if (t < 64) {
        float s = part[0][t] + part[1][t] + part[2][t] + part[3][t] + b2[t];
        out[b * 64 + t] = 1.0f / (1.0f + expf(-s));
    }
}

extern "C" void kernel_launch(void* const* d_in, const int* in_sizes, int n_in,
                              void* d_out, int out_size, void* d_ws, size_t ws_size,
                              hipStream_t stream) {
    const float* params = (const float*)d_in[0];
    const float* w0r = (const float*)d_in[1];
    const float* w0i = (const float*)d_in[2];
    const float* w1r = (const float*)d_in[3];
    const float* w1i = (const float*)d_in[4];
    const float* w2r = (const float*)d_in[5];
    const float* w2i = (const float*)d_in[6];
    const float* lin1w = (const float*)d_in[7];
    const float* lin1b = (const float*)d_in[8];
    const float* lin2w = (const float*)d_in[9];
    const float* lin2b = (const float*)d_in[10];
    char* ws = (char*)d_ws;
    float* out = (float*)d_out;

    k_misc<<<562, 256, 0, stream>>>(w0r, w0i, w1r, w1i, w2r, w2i, lin2w, ws);
    k_prep<<<1, 256, 0, stream>>>(ws);
    k_s<<<1000, 512, 0, stream>>>(params, ws);
    k_E<<<4000, 512, 0, stream>>>(lin1w, ws);
    k_gemm<<<dim3(16, 32, 4), 128, 0, stream>>>(ws);
    k_final<<<512, 256, 0, stream>>>(lin1w, lin1b, lin2b, out, ws);
}

// Round 17
// 104.998 us; speedup vs baseline: 1.0852x; 1.0249x over previous
//
#include <hip/hip_runtime.h>
#include <math.h>

#define NB 512
#define MODES 1000
#define PI_D 3.14159265358979323846

// ws layout (bytes)
#define OFF_PART   0          // double2[192] per-(k,m) weight row sums
#define OFF_SCAL   4096       // double[4]: c0re,c0im,c1re,c1im
#define OFF_T2RE   4224       // double[64]
#define OFF_T2IM   4736       // double[64]
#define OFF_GP     5248       // float[64]  g(+1)
#define OFF_CNT    5504       // int irregular count
#define OFF_W2T    16384      // float[64000]  W2 transposed [o][j]
#define OFF_S2     2621440    // float[512000] s2 value [b*1000+f]
#define OFF_IRR    4718592    // int[512000] irregular indices
#define OFF_SG     13107200   // float[512*1000] sgn [b][f] row-major
#define OFF_EHI    19398656   // ushort[1024*1024] bf16 hi of E[o][f]
#define OFF_ELO    21495808   // ushort[1024*1024] bf16 lo of E[o][f]
#define OFF_SGNB   23592960   // ushort[512*1024] bf16 sgn [b][f], f>=1000 zero
#define OFF_H      24641536   // float[4][512][1024] split-K partials (8 MB)
#define HP_STRIDE  524288     // 512*1024 floats

typedef short short8 __attribute__((ext_vector_type(8)));
typedef float f32x4 __attribute__((ext_vector_type(4)));

__device__ __forceinline__ double retanh_d(double a, double b) {
    if (fabs(a) > 20.0) return a > 0.0 ? 1.0 : -1.0;
    double e2 = exp(2.0 * a);
    double em2 = 1.0 / e2;
    return (e2 - em2) / (e2 + em2 + 2.0 * cos(2.0 * b));
}

__device__ __forceinline__ unsigned short f2bf(float x) {
    unsigned u = __float_as_uint(x);
    unsigned r = (u + 0x7FFFu + ((u >> 16) & 1u)) >> 16;
    return (unsigned short)r;
}

// Preamble: bid<192 row sums; 192..441 W2 transpose; 442..489 EHI row-pad;
// 490..537 ELO row-pad; 538..561 sgnb f-pad.
__global__ void k_misc(const float* __restrict__ w0r, const float* __restrict__ w0i,
                       const float* __restrict__ w1r, const float* __restrict__ w1i,
                       const float* __restrict__ w2r, const float* __restrict__ w2i,
                       const float* __restrict__ w2, char* ws) {
    int bid = blockIdx.x, t = threadIdx.x;
    if (bid < 192) {
        int k = bid >> 6, m = bid & 63;
        const float* wr = (k == 0) ? w0r : (k == 1) ? w1r : w2r;
        const float* wi = (k == 0) ? w0i : (k == 1) ? w1i : w2i;
        double sr = 0.0, si = 0.0;
        for (int c = t; c < MODES; c += 256) {
            sr += (double)wr[m * MODES + c];
            si += (double)wi[m * MODES + c];
        }
        __shared__ double lr[256], li[256];
        lr[t] = sr; li[t] = si; __syncthreads();
        for (int s = 128; s > 0; s >>= 1) {
            if (t < s) { lr[t] += lr[t + s]; li[t] += li[t + s]; }
            __syncthreads();
        }
        if (t == 0) {
            double2* p = (double2*)(ws + OFF_PART);
            p[k * 64 + m] = make_double2(lr[0], li[0]);
        }
    } else if (bid < 442) {
        int idx = (bid - 192) * 256 + t;   // < 64000
        int o = idx >> 6, j = idx & 63;
        ((float*)(ws + OFF_W2T))[idx] = w2[j * MODES + o];
    } else if (bid < 490) {
        int idx = (bid - 442) * 256 + t;   // rows 1000..1023 of EHI
        ((unsigned*)(ws + OFF_EHI))[512000 + idx] = 0u;
    } else if (bid < 538) {
        int idx = (bid - 490) * 256 + t;
        ((unsigned*)(ws + OFF_ELO))[512000 + idx] = 0u;
    } else {
        int idx = (bid - 538) * 256 + t;   // < 6144
        if (idx < 6144) {
            int b = idx / 12, u = idx % 12;
            ((unsigned*)(ws + OFF_SGNB))[b * 512 + 500 + u] = 0u;
        }
    }
}

// c0,c1 totals; T2 via 64-pt inverse DFT with LDS twiddle table; gp = g(+1); cnt = 0.
__global__ void k_prep(char* ws) {
    int t = threadIdx.x;           // 256
    int j = t & 63, q = t >> 6;    // q in 0..3
    double2* part = (double2*)(ws + OFF_PART);
    double* scal  = (double*)(ws + OFF_SCAL);
    double* t2re  = (double*)(ws + OFF_T2RE);
    double* t2im  = (double*)(ws + OFF_T2IM);
    float*  gp    = (float*)(ws + OFF_GP);
    __shared__ double a1[128], a2[128];
    __shared__ double sre[64], sim[64];
    __shared__ double tc[64], tsn[64];
    __shared__ double pr[4][64], pi_[4][64];
    if (t < 128) {
        double2 v = part[t];       // k = t>>6, m = t&63
        a1[t] = v.x; a2[t] = v.y;
    }
    if (t < 64) {
        double2 v = part[128 + t];
        sre[t] = v.x; sim[t] = v.y;
    }
    if (t >= 128 && t < 192) {     // twiddle table: one sincos per lane
        int r = t - 128;
        double s, c;
        sincos((double)r * (PI_D / 32.0), &s, &c);
        tc[r] = c; tsn[r] = s;
    }
    __syncthreads();
    for (int s = 32; s > 0; s >>= 1) {
        if (t < 128 && (t & 63) < s) { a1[t] += a1[t + s]; a2[t] += a2[t + s]; }
        __syncthreads();
    }
    if (t < 2) { scal[2 * t] = a1[t * 64]; scal[2 * t + 1] = a2[t * 64]; }
    double tr = 0.0, ti = 0.0;
    for (int mm = q * 16; mm < q * 16 + 16; ++mm) {
        int r = (j * mm) & 63;
        double c = tc[r], s = tsn[r];
        tr += sre[mm] * c - sim[mm] * s;
        ti += sre[mm] * s + sim[mm] * c;
    }
    pr[q][j] = tr; pi_[q][j] = ti;
    __syncthreads();
    if (t < 64) {
        double trr = pr[0][t] + pr[1][t] + pr[2][t] + pr[3][t];
        double tii = pi_[0][t] + pi_[1][t] + pi_[2][t] + pi_[3][t];
        t2re[t] = trr; t2im[t] = tii;
        gp[t] = (float)retanh_d(trr, tii);
    }
    if (t == 0) *(int*)(ws + OFF_CNT) = 0;
}

// Fused stage 3: bid<4000 = E-stream unit (8 hoisted clamped loads);
// bid>=4000 = s2/sgn gather unit. Both depend only on k_prep.
__global__ void __launch_bounds__(512) k_sE(const float* __restrict__ w1,
                                            const float* __restrict__ params,
                                            char* ws) {
    int bid = blockIdx.x, t = threadIdx.x;
    if (bid < 4000) {
        int o = bid >> 2, chunk = bid & 3;
        const float4* w4 = (const float4*)w1;
        const float4* gp4 = (const float4*)(ws + OFF_GP);
        float4 g = gp4[t & 15];
        unsigned short* ehi = (unsigned short*)(ws + OFF_EHI);
        unsigned short* elo = (unsigned short*)(ws + OFF_ELO);
        size_t rowbase = (size_t)o * 16000;
        int cbase = chunk * 4096 + t;
        float4 v[8];
#pragma unroll
        for (int k = 0; k < 8; ++k) {
            int gidx = cbase + k * 512;
            int cidx = (gidx < 15999) ? gidx : 15999;
            v[k] = w4[rowbase + cidx];
        }
#pragma unroll
        for (int k = 0; k < 8; ++k) {
            int gidx = cbase + k * 512;
            float a = v[k].x * g.x + v[k].y * g.y + v[k].z * g.z + v[k].w * g.w;
            a = (gidx < 16000) ? a : 0.0f;
            a += __shfl_xor(a, 1);
            a += __shfl_xor(a, 2);
            a += __shfl_xor(a, 4);
            a += __shfl_xor(a, 8);
            if ((t & 15) == 0) {
                int f = chunk * 256 + k * 32 + (t >> 4);  // <= 1023
                unsigned short hi = f2bf(a);
                float hif = __uint_as_float((unsigned)hi << 16);
                unsigned short lo = f2bf(a - hif);
                ehi[(size_t)o * 1024 + f] = hi;
                elo[(size_t)o * 1024 + f] = lo;
            }
        }
    } else {
        int idx = (bid - 4000) * 512 + t;   // < 512000
        const double* scal = (const double*)(ws + OFF_SCAL);
        double c0r = scal[0], c0i = scal[1], c1r = scal[2], c1i = scal[3];
        float p0 = params[(size_t)idx * 64];
        double s1 = retanh_d((double)p0 * c0r, (double)p0 * c0i);
        float s1f = (float)s1;
        double s2 = retanh_d((double)s1f * c1r, (double)s1f * c1i);
        float s2f = (float)s2;
        float sg; bool irr = false;
        if (s2f == 1.0f)       sg = 1.0f;
        else if (s2f == -1.0f) sg = -1.0f;
        else { sg = (s2f >= 0.0f) ? 1.0f : -1.0f; irr = true; }
        ((float*)(ws + OFF_SG))[idx] = sg;
        ((float*)(ws + OFF_S2))[idx] = s2f;
        int b = idx / 1000, f = idx - b * 1000;
        ((unsigned short*)(ws + OFF_SGNB))[(size_t)b * 1024 + f] =
            (sg > 0.0f) ? (unsigned short)0x3F80 : (unsigned short)0xBF80;
        if (irr) {
            int pos = atomicAdd((int*)(ws + OFF_CNT), 1);
            ((int*)(ws + OFF_IRR))[pos] = idx;
        }
    }
}

// hp[z][b][o] += sum over K-chunk z: split-K x4 MFMA, 4096 waves (4/SIMD).
__global__ void __launch_bounds__(128) k_gemm(char* ws) {
    const unsigned short* sgnb = (const unsigned short*)(ws + OFF_SGNB);
    const unsigned short* ehi  = (const unsigned short*)(ws + OFF_EHI);
    const unsigned short* elo  = (const unsigned short*)(ws + OFF_ELO);
    int strip = blockIdx.x;      // 0..15  (64 o-cols)
    int btile = blockIdx.y;      // 0..31  (16 b-rows)
    int z     = blockIdx.z;      // 0..3   (K-chunk of 256)
    float* hp = (float*)(ws + OFF_H) + (size_t)z * HP_STRIDE;
    int t = threadIdx.x;         // 128 = 2 waves
    int wave = t >> 6, l = t & 63;
    int rc = l & 15, grp = l >> 4;
    int b0 = btile * 16;
    int o0 = strip * 64 + wave * 32;
    f32x4 acc0 = {0.f, 0.f, 0.f, 0.f}, acc1 = {0.f, 0.f, 0.f, 0.f};
    const unsigned short* ap  = sgnb + (size_t)(b0 + rc) * 1024 + z * 256 + grp * 8;
    const unsigned short* bh0 = ehi + (size_t)(o0 + rc) * 1024 + z * 256 + grp * 8;
    const unsigned short* bl0 = elo + (size_t)(o0 + rc) * 1024 + z * 256 + grp * 8;
#pragma unroll
    for (int s = 0; s < 8; ++s) {
        short8 af  = *(const short8*)(ap + s * 32);
        short8 h0  = *(const short8*)(bh0 + s * 32);
        short8 l0  = *(const short8*)(bl0 + s * 32);
        short8 h1  = *(const short8*)(bh0 + 16 * 1024 + s * 32);
        short8 l1  = *(const short8*)(bl0 + 16 * 1024 + s * 32);
        acc0 = __builtin_amdgcn_mfma_f32_16x16x32_bf16(af, h0, acc0, 0, 0, 0);
        acc0 = __builtin_amdgcn_mfma_f32_16x16x32_bf16(af, l0, acc0, 0, 0, 0);
        acc1 = __builtin_amdgcn_mfma_f32_16x16x32_bf16(af, h1, acc1, 0, 0, 0);
        acc1 = __builtin_amdgcn_mfma_f32_16x16x32_bf16(af, l1, acc1, 0, 0, 0);
    }
    // C/D: col = lane&15, row = (lane>>4)*4 + reg   [m89-verified]
#pragma unroll
    for (int r = 0; r < 4; ++r) {
        hp[(size_t)(b0 + grp * 4 + r) * 1024 + o0 + rc]      = acc0[r];
        hp[(size_t)(b0 + grp * 4 + r) * 1024 + o0 + 16 + rc] = acc1[r];
    }
}

// Fused epilogue: h = sum_z hp + b1; rare exact corrections; tanh; dot W2t; sigmoid.
__global__ void k_final(const float* __restrict__ w1, const float* __restrict__ b1,
                        const float* __restrict__ b2, float* __restrict__ out, char* ws) {
    int b = blockIdx.x, t = threadIdx.x;   // 512 blocks x 256
    const float* hp = (const float*)(ws + OFF_H);
    __shared__ float h[MODES];
    __shared__ float part[4][64];
    __shared__ __align__(16) float cv[64];
    for (int o = t; o < MODES; o += 256) {
        size_t base = (size_t)b * 1024 + o;
        h[o] = hp[base] + hp[base + HP_STRIDE] + hp[base + 2 * HP_STRIDE]
             + hp[base + 3 * HP_STRIDE] + b1[o];
    }
    __syncthreads();
    int cnt = *(const int*)(ws + OFF_CNT);
    if (cnt > 0) {
        const int* irr     = (const int*)(ws + OFF_IRR);
        const float* s2a   = (const float*)(ws + OFF_S2);
        const float* sgn   = (const float*)(ws + OFF_SG);
        const double* t2re = (const double*)(ws + OFF_T2RE);
        const double* t2im = (const double*)(ws + OFF_T2IM);
        const float* gp    = (const float*)(ws + OFF_GP);
        for (int e = 0; e < cnt; ++e) {
            int idx = irr[e];
            int bb = idx / 1000;
            if (bb != b) continue;              // uniform per block
            int f = idx - bb * 1000;
            float s2 = s2a[idx];
            float sg = sgn[idx];
            if (t < 64) {
                double g = retanh_d((double)s2 * t2re[t], (double)s2 * t2im[t]);
                cv[t] = (float)g - sg * gp[t];
            }
            __syncthreads();
            const float4* w4 = (const float4*)w1;
            const float4* c4 = (const float4*)cv;
            for (int o = t; o < MODES; o += 256) {
                size_t base = (size_t)o * 16000 + (size_t)f * 16;
                float a = 0.0f;
#pragma unroll
                for (int r = 0; r < 16; ++r) {
                    float4 w = w4[base + r];
                    float4 c = c4[r];
                    a += w.x * c.x + w.y * c.y + w.z * c.z + w.w * c.w;
                }
                h[o] += a;
            }
            __syncthreads();
        }
    }
    for (int o = t; o < MODES; o += 256) h[o] = tanhf(h[o]);
    __syncthreads();
    const float* w2t = (const float*)(ws + OFF_W2T);
    int j = t & 63, c = t >> 6;
    float acc = 0.0f;
    for (int o = c * 250; o < c * 250 + 250; ++o) acc += h[o] * w2t[o * 64 + j];
    part[c][j] = acc;
    __syncthreads();
    if (t < 64) {
        float s = part[0][t] + part[1][t] + part[2][t] + part[3][t] + b2[t];
        out[b * 64 + t] = 1.0f / (1.0f + expf(-s));
    }
}

extern "C" void kernel_launch(void* const* d_in, const int* in_sizes, int n_in,
                              void* d_out, int out_size, void* d_ws, size_t ws_size,
                              hipStream_t stream) {
    const float* params = (const float*)d_in[0];
    const float* w0r = (const float*)d_in[1];
    const float* w0i = (const float*)d_in[2];
    const float* w1r = (const float*)d_in[3];
    const float* w1i = (const float*)d_in[4];
    const float* w2r = (const float*)d_in[5];
    const float* w2i = (const float*)d_in[6];
    const float* lin1w = (const float*)d_in[7];
    const float* lin1b = (const float*)d_in[8];
    const float* lin2w = (const float*)d_in[9];
    const float* lin2b = (const float*)d_in[10];
    char* ws = (char*)d_ws;
    float* out = (float*)d_out;

    k_misc<<<562, 256, 0, stream>>>(w0r, w0i, w1r, w1i, w2r, w2i, lin2w, ws);
    k_prep<<<1, 256, 0, stream>>>(ws);
    k_sE<<<5000, 512, 0, stream>>>(lin1w, params, ws);
    k_gemm<<<dim3(16, 32, 4), 128, 0, stream>>>(ws);
    k_final<<<512, 256, 0, stream>>>(lin1w, lin1b, lin2b, out, ws);
}